// Round 16
// baseline (1749.096 us; speedup 1.0000x reference)
//
#include <hip/hip_runtime.h>
#include <math.h>
#include <stdint.h>

// Llama forward on MI355X. Round 16: nontemporal stores for the logits f32 output
// in gemm4 (write-only 524MB stream was evicting hb/logT from L2/L3 -> 355MB
// over-fetch). Sole change vs round 15 (1740us best).

using short8v = __attribute__((ext_vector_type(8))) short;
using f32x4   = __attribute__((ext_vector_type(4))) float;

__device__ __forceinline__ float b2f(short s) {
    union { unsigned u; float f; } v; v.u = ((unsigned)(unsigned short)s) << 16; return v.f;
}
__device__ __forceinline__ short f2b(float f) {
    union { float f; unsigned u; } v; v.f = f;
    unsigned r = v.u + 0x7FFFu + ((v.u >> 16) & 1u);
    return (short)(r >> 16);
}

__device__ __forceinline__ void mfma_n(f32x4& d, short8v a, short8v b) {
    asm("v_mfma_f32_16x16x32_bf16 %0, %1, %2, %0" : "+v"(d) : "v"(a), "v"(b));
}
__device__ __forceinline__ void mfma_f(f32x4& d, short8v a, short8v b) {
    asm("s_nop 1\n\tv_mfma_f32_16x16x32_bf16 %0, %1, %2, %0" : "+v"(d) : "v"(a), "v"(b));
}
#define MFMA_FENCE() do { __builtin_amdgcn_sched_barrier(0); \
    asm volatile("s_nop 7\n\ts_nop 7"); \
    __builtin_amdgcn_sched_barrier(0); } while (0)

__device__ __forceinline__ void gload16(const void* g, void* l) {
    __builtin_amdgcn_global_load_lds(
        (const __attribute__((address_space(1))) unsigned int*)(uintptr_t)g,
        (__attribute__((address_space(3))) unsigned int*)(uintptr_t)l,
        16, 0, 0);
}

#define BARX() do { asm volatile("" ::: "memory"); \
    __builtin_amdgcn_s_barrier(); asm volatile("" ::: "memory"); } while (0)
#define VMN(n) asm volatile("s_waitcnt vmcnt(" #n ")" ::: "memory")
#define LGKM0() do { asm volatile("s_waitcnt lgkmcnt(0)" ::: "memory"); \
    __builtin_amdgcn_sched_barrier(0); } while (0)

// ---------------- rope tables ----------------
__global__ void rope_table_k(float* __restrict__ ct, float* __restrict__ st) {
    int i = blockIdx.x * 256 + threadIdx.x;
    int n = i >> 5, j = i & 31;
    float freq = expf(-(float)j * (9.210340371976184f / 32.f));
    float a = (float)n * freq;
    ct[i] = cosf(a);
    st[i] = sinf(a);
}

// ---------------- embedding gather ----------------
__global__ void embed_k(const int* __restrict__ tok, const float* __restrict__ emb,
                        float* __restrict__ x) {
    int row = blockIdx.x;
    int tk = tok[row];
    const float4* src = (const float4*)(emb + (size_t)tk * 1024);
    float4* dst = (float4*)(x + (size_t)row * 1024);
    dst[threadIdx.x] = src[threadIdx.x];
}

// ---------------- weight convert+transpose: f32 [K][N] -> bf16 [rows][Kpad] ----------------
__global__ void wconv_k(const float* __restrict__ W, short* __restrict__ T,
                        int K, int N, int Kpad,
                        size_t w_lstride, size_t t_lstride, int ilv) {
    W += blockIdx.z * w_lstride;
    T += blockIdx.z * t_lstride;
    int n0 = blockIdx.x * 32, k0 = blockIdx.y * 32;
    __shared__ float tile[32][33];
    int t = threadIdx.x;
    int kk = t >> 3, ns = (t & 7) * 4;
    float4 v = make_float4(0.f, 0.f, 0.f, 0.f);
    int gk = k0 + kk;
    if (gk < K) {
        if (n0 + ns + 3 < N) {
            v = *(const float4*)(W + (size_t)gk * N + n0 + ns);
        } else {
            float tmp[4] = {0.f, 0.f, 0.f, 0.f};
            #pragma unroll
            for (int j = 0; j < 4; ++j)
                if (n0 + ns + j < N) tmp[j] = W[(size_t)gk * N + n0 + ns + j];
            v = make_float4(tmp[0], tmp[1], tmp[2], tmp[3]);
        }
    }
    tile[kk][ns + 0] = v.x; tile[kk][ns + 1] = v.y;
    tile[kk][ns + 2] = v.z; tile[kk][ns + 3] = v.w;
    __syncthreads();
    int nn = t >> 3, ks = (t & 7) * 4;
    short o[4];
    #pragma unroll
    for (int j = 0; j < 4; ++j) o[j] = f2b(tile[ks + j][nn]);
    int oc = n0 + nn;
    int dr = oc;
    if (ilv) {
        if (oc < 2730) dr = ((oc >> 4) << 5) + (oc & 15);
        else { int jj = oc - 2730; dr = ((jj >> 4) << 5) + 16 + (jj & 15); }
    }
    *(int2*)(T + (size_t)dr * Kpad + k0 + ks) = *(int2*)o;
}

// ---------------- rmsnorm: f32 in -> bf16 out ----------------
__global__ void rmsnorm_k(const float* __restrict__ x, const float* __restrict__ wt,
                          short* __restrict__ out) {
    int row = blockIdx.x;
    int t = threadIdx.x;
    const float* xr = x + (size_t)row * 1024;
    float4 v = ((const float4*)xr)[t];
    float ss = v.x * v.x + v.y * v.y + v.z * v.z + v.w * v.w;
    #pragma unroll
    for (int off = 32; off > 0; off >>= 1) ss += __shfl_down(ss, off, 64);
    __shared__ float red[4];
    if ((t & 63) == 0) red[t >> 6] = ss;
    __syncthreads();
    float tot = red[0] + red[1] + red[2] + red[3];
    float inv = rsqrtf(tot * (1.f / 1024.f) + 1.1920929e-7f);
    float4 wv = ((const float4*)wt)[t];
    int2 pk;
    pk.x = (int)(unsigned short)f2b(v.x * inv * wv.x) |
           ((int)(unsigned short)f2b(v.y * inv * wv.y) << 16);
    pk.y = (int)(unsigned short)f2b(v.z * inv * wv.z) |
           ((int)(unsigned short)f2b(v.w * inv * wv.w) << 16);
    *(int2*)(out + (size_t)row * 1024 + t * 4) = pk;
}

// ---------------- gemm2h: 64x128 drain-style, 4 blocks/CU (wo, ff2) ----------------
template <bool BIAS, bool RES, bool OUTBF16>
__global__ __launch_bounds__(256, 4) void gemm2h(
    const short* __restrict__ A, const short* __restrict__ Bt,
    const float* __restrict__ bias, const float* __restrict__ res,
    void* __restrict__ outp, int N, int lda, int ldb, int ksteps) {
    __shared__ __align__(16) short As[64 * 32];
    __shared__ __align__(16) short Bs[128 * 32];
    const int t = threadIdx.x;
    const int lane = t & 63;
    const int w = t >> 6, wm = w >> 1, wn = w & 1;
    const int c = lane & 15, g = lane >> 4;

    const int nwg = (int)gridDim.x;
    const int cpx = nwg >> 3;
    const int wg = ((int)blockIdx.x & 7) * cpx + ((int)blockIdx.x >> 3);
    const int m0 = (wg & 63) << 6;
    const int n0 = (wg >> 6) << 7;

    const int srow = w * 16 + (lane >> 2);
    const int sseg = (lane & 3) * 8;
    const short* ga0 = A  + (size_t)(m0 + srow) * lda + sseg;
    const short* gb0 = Bt + (size_t)(n0 + w * 32 + (lane >> 2)) * ldb + sseg;
    const short* gb1 = Bt + (size_t)(n0 + w * 32 + 16 + (lane >> 2)) * ldb + sseg;
    short* la0 = &As[w * 512];
    short* lb0 = &Bs[(w * 2 + 0) * 512];
    short* lb1 = &Bs[(w * 2 + 1) * 512];

    f32x4 acc[2][4] = {};

    for (int kt = 0; kt < ksteps; ++kt) {
        const int k0 = kt << 5;
        __syncthreads();
        gload16(ga0 + k0, la0);
        gload16(gb0 + k0, lb0);
        gload16(gb1 + k0, lb1);
        __syncthreads();
        short8v af[2], bf[4];
        #pragma unroll
        for (int mi = 0; mi < 2; ++mi)
            af[mi] = *(const short8v*)&As[(wm * 32 + mi * 16 + c) * 32 + g * 8];
        #pragma unroll
        for (int ni = 0; ni < 4; ++ni)
            bf[ni] = *(const short8v*)&Bs[(wn * 64 + ni * 16 + c) * 32 + g * 8];
        #pragma unroll
        for (int mi = 0; mi < 2; ++mi)
            #pragma unroll
            for (int ni = 0; ni < 4; ++ni)
                mfma_n(acc[mi][ni], af[mi], bf[ni]);
    }
    MFMA_FENCE();
    #pragma unroll
    for (int mi = 0; mi < 2; ++mi) {
        #pragma unroll
        for (int ni = 0; ni < 4; ++ni) {
            int col = n0 + wn * 64 + ni * 16 + c;
            if (col < N) {
                float bv = BIAS ? bias[col] : 0.f;
                #pragma unroll
                for (int i = 0; i < 4; ++i) {
                    int row = m0 + wm * 32 + mi * 16 + g * 4 + i;
                    size_t off = (size_t)row * N + col;
                    float v = acc[mi][ni][i] + bv;
                    if (RES) v += res[off];
                    if (OUTBF16) ((short*)outp)[off] = f2b(v);
                    else         ((float*)outp)[off] = v;
                }
            }
        }
    }
}

// ---------------- gemm3: 8-phase counted-vmcnt 128x256, BK=64, 8 waves ----------------
// EPI: 0 = plain epilogue, 1 = rope (qkv), 2 = geglu (ff1, interleaved layout).
template <bool BIAS, bool RES, bool OUTBF16, int EPI>
__global__ __launch_bounds__(512, 1) void gemm3(
    const short* __restrict__ A, const short* __restrict__ Bt,
    const float* __restrict__ bias, const float* __restrict__ res,
    void* __restrict__ outp, int N, int lda, int ldb, int nrowsB, int KT,
    const float* __restrict__ ct, const float* __restrict__ st,
    short* __restrict__ vtb) {
    __shared__ __align__(16) short L[49152];
    const int t = threadIdx.x;
    const int lane = t & 63;
    const int w = t >> 6;
    const int wm = w >> 2, wn = w & 3;
    const int c = lane & 15, g = lane >> 4;

    const int nwg = (int)gridDim.x, cpx = nwg >> 3;
    const int wg = ((int)blockIdx.x & 7) * cpx + ((int)blockIdx.x >> 3);
    const int m0 = (wg & 31) << 7;
    const int n0 = (wg >> 5) << 8;

    const int rS = t >> 3, sS = t & 7;
    const int sSw = (sS ^ (rS & 7)) << 3;
    size_t aoffh[2], broff[2][2];
    #pragma unroll
    for (int h = 0; h < 2; ++h)
        aoffh[h] = (size_t)(m0 + h * 64 + rS) * lda + sSw;
    #pragma unroll
    for (int h = 0; h < 2; ++h)
        #pragma unroll
        for (int i = 0; i < 2; ++i) {
            int brow = n0 + h * 128 + rS + i * 64;
            if (brow > nrowsB - 1) brow = nrowsB - 1;
            broff[h][i] = (size_t)brow * ldb + sSw;
        }
    short* ldsA[2][2];
    short* ldsB[2][2];
    #pragma unroll
    for (int p = 0; p < 2; ++p)
        #pragma unroll
        for (int h = 0; h < 2; ++h) {
            ldsA[p][h] = &L[(p * 2 + h) * 4096 + w * 512];
            ldsB[p][h] = &L[16384 + (p * 2 + h) * 8192 + w * 512];
        }

    const int cb0 = ((g * 8) ^ ((c & 7) * 8));
    const int vbA0 = wm * 4096 + c * 64 + cb0;
    const int vbA1 = vbA0 ^ 32;
    const int vbB0 = 16384 + (wn >> 1) * 8192 + (wn & 1) * 4096 + c * 64 + cb0;
    const int vbB1 = vbB0 ^ 32;

    #define STA3(p, h, kt) gload16(A + aoffh[h] + (kt) * 64, ldsA[p][h])
    #define STB3(p, h, kt) do { \
        gload16(Bt + broff[h][0] + (kt) * 64, ldsB[p][h]); \
        gload16(Bt + broff[h][1] + (kt) * 64, ldsB[p][h] + 4096); } while (0)
    #define LDA3(p, mi, ks) (*(const short8v*)&L[(p) * 8192 + (mi) * 1024 + ((ks) ? vbA1 : vbA0)])
    #define LDB3(p, ni, ks) (*(const short8v*)&L[(p) * 16384 + (ni) * 1024 + ((ks) ? vbB1 : vbB0)])
    #define MFMA8(MLO, NLO, BV) do { \
        _Pragma("unroll") for (int ks_ = 0; ks_ < 2; ++ks_) \
        _Pragma("unroll") for (int mi_ = 0; mi_ < 2; ++mi_) \
        _Pragma("unroll") for (int ni_ = 0; ni_ < 2; ++ni_) \
            mfma_n(acc[(MLO) + mi_][(NLO) + ni_], av[(MLO) + mi_][ks_], BV[(NLO) + ni_][ks_]); \
        } while (0)

    f32x4 acc[4][4] = {};
    short8v av[4][2], bc[4][2], bn[4][2];

    STB3(0, 1, 0); STB3(0, 0, 0); STA3(0, 0, 0); STA3(0, 1, 0);
    STB3(1, 1, 1); STB3(1, 0, 1); STA3(1, 0, 1); STA3(1, 1, 1);
    VMN(6);
    BARX();
    #pragma unroll
    for (int ni = 0; ni < 4; ++ni)
        #pragma unroll
        for (int ks = 0; ks < 2; ++ks)
            bc[ni][ks] = LDB3(0, ni, ks);
    LGKM0();
    BARX();
    asm volatile("s_nop 7\n\ts_nop 7");

    for (int KB = 0; KB < KT; KB += 2) {
        const bool st1 = (KB + 2 < KT);
        const bool st2 = (KB + 3 < KT);
        // ph1
        #pragma unroll
        for (int mi = 0; mi < 2; ++mi)
            #pragma unroll
            for (int ks = 0; ks < 2; ++ks) av[mi][ks] = LDA3(0, mi, ks);
        if (st1) STB3(0, 1, KB + 2);
        BARX();
        __builtin_amdgcn_s_setprio(1); MFMA8(0, 0, bc); __builtin_amdgcn_s_setprio(0);
        BARX();
        // ph2
        #pragma unroll
        for (int mi = 2; mi < 4; ++mi)
            #pragma unroll
            for (int ks = 0; ks < 2; ++ks) av[mi][ks] = LDA3(0, mi, ks);
        if (st1) { STB3(0, 0, KB + 2); VMN(6); } else { VMN(2); }
        BARX();
        __builtin_amdgcn_s_setprio(1); MFMA8(2, 0, bc); __builtin_amdgcn_s_setprio(0);
        BARX();
        // ph3
        #pragma unroll
        for (int ni = 0; ni < 2; ++ni)
            #pragma unroll
            for (int ks = 0; ks < 2; ++ks) bn[ni][ks] = LDB3(1, ni, ks);
        if (st1) STA3(0, 0, KB + 2);
        BARX();
        __builtin_amdgcn_s_setprio(1); MFMA8(0, 2, bc); __builtin_amdgcn_s_setprio(0);
        BARX();
        // ph4
        #pragma unroll
        for (int ni = 2; ni < 4; ++ni)
            #pragma unroll
            for (int ks = 0; ks < 2; ++ks) bn[ni][ks] = LDB3(1, ni, ks);
        if (st1) { STA3(0, 1, KB + 2); VMN(6); } else { VMN(0); }
        BARX();
        __builtin_amdgcn_s_setprio(1); MFMA8(2, 2, bc); __builtin_amdgcn_s_setprio(0);
        BARX();
        // ph5
        #pragma unroll
        for (int mi = 0; mi < 2; ++mi)
            #pragma unroll
            for (int ks = 0; ks < 2; ++ks) av[mi][ks] = LDA3(1, mi, ks);
        if (st2) STB3(1, 1, KB + 3);
        BARX();
        __builtin_amdgcn_s_setprio(1); MFMA8(0, 0, bn); __builtin_amdgcn_s_setprio(0);
        BARX();
        // ph6
        #pragma unroll
        for (int mi = 2; mi < 4; ++mi)
            #pragma unroll
            for (int ks = 0; ks < 2; ++ks) av[mi][ks] = LDA3(1, mi, ks);
        if (st2) STB3(1, 0, KB + 3);
        if (st1) VMN(6);
        BARX();
        __builtin_amdgcn_s_setprio(1); MFMA8(2, 0, bn); __builtin_amdgcn_s_setprio(0);
        BARX();
        // ph7
        if (st1) {
            #pragma unroll
            for (int ni = 0; ni < 2; ++ni)
                #pragma unroll
                for (int ks = 0; ks < 2; ++ks) bc[ni][ks] = LDB3(0, ni, ks);
        }
        if (st2) STA3(1, 0, KB + 3);
        BARX();
        __builtin_amdgcn_s_setprio(1); MFMA8(0, 2, bn); __builtin_amdgcn_s_setprio(0);
        BARX();
        // ph8
        if (st1) {
            #pragma unroll
            for (int ni = 2; ni < 4; ++ni)
                #pragma unroll
                for (int ks = 0; ks < 2; ++ks) bc[ni][ks] = LDB3(0, ni, ks);
        }
        if (st2) STA3(1, 1, KB + 3);
        if (st1) VMN(6);
        BARX();
        __builtin_amdgcn_s_setprio(1); MFMA8(2, 2, bn); __builtin_amdgcn_s_setprio(0);
        BARX();
    }

    MFMA_FENCE();

    if (EPI == 1) {
        const int colbase = n0 + wn * 64;
        const int sec = colbase >> 10;
        if (sec < 2) {
            const float sc = (sec == 0) ? 0.18033688011112042f : 1.0f;
            #pragma unroll
            for (int mi = 0; mi < 4; ++mi)
                #pragma unroll
                for (int ni = 0; ni < 2; ++ni) {
                    const int col = colbase + ni * 16 + c;
                    const int jj = ni * 16 + c;
                    #pragma unroll
                    for (int i = 0; i < 4; ++i) {
                        int row = m0 + wm * 64 + mi * 16 + g * 4 + i;
                        int n = row & 2047;
                        float cv = ct[n * 32 + jj], sv = st[n * 32 + jj];
                        float a = acc[mi][ni][i], b = acc[mi][ni + 2][i];
                        ((short*)outp)[(size_t)row * N + col]      = f2b((a * cv - b * sv) * sc);
                        ((short*)outp)[(size_t)row * N + col + 32] = f2b((b * cv + a * sv) * sc);
                    }
                }
        } else {
            const int h64 = (colbase - 2048) >> 6;
            #pragma unroll
            for (int mi = 0; mi < 4; ++mi) {
                const int r0 = m0 + wm * 64 + mi * 16 + g * 4;
                const int bb = r0 >> 11, nn = r0 & 2047;
                #pragma unroll
                for (int ni = 0; ni < 4; ++ni) {
                    const int d = ni * 16 + c;
                    short s4[4];
                    #pragma unroll
                    for (int i = 0; i < 4; ++i) s4[i] = f2b(acc[mi][ni][i]);
                    *(int2*)(vtb + (size_t)((bb * 16 + h64) * 64 + d) * 2048 + nn) =
                        *(int2*)s4;
                }
            }
        }
        return;
    }

    if (EPI == 2) {
        const int colbase = n0 + wn * 64;
        #pragma unroll
        for (int np = 0; np < 2; ++np) {
            const int j = ((colbase >> 5) + np) * 16 + c;
            if (j < 2730) {
                const float bu = bias[j], bg = bias[2730 + j];
                #pragma unroll
                for (int mi = 0; mi < 4; ++mi)
                    #pragma unroll
                    for (int i = 0; i < 4; ++i) {
                        int row = m0 + wm * 64 + mi * 16 + g * 4 + i;
                        float u1v = acc[mi][2 * np][i] + bu;
                        float gv  = acc[mi][2 * np + 1][i] + bg;
                        float val = 0.5f * gv * (1.f + erff(gv * 0.7071067811865475f)) * u1v;
                        ((short*)outp)[(size_t)row * 2752 + j] = f2b(val);
                    }
            } else if (j < 2752) {
                #pragma unroll
                for (int mi = 0; mi < 4; ++mi)
                    #pragma unroll
                    for (int i = 0; i < 4; ++i) {
                        int row = m0 + wm * 64 + mi * 16 + g * 4 + i;
                        ((short*)outp)[(size_t)row * 2752 + j] = 0;
                    }
            }
        }
        return;
    }

    #pragma unroll
    for (int mi = 0; mi < 4; ++mi) {
        #pragma unroll
        for (int ni = 0; ni < 4; ++ni) {
            int col = n0 + wn * 64 + ni * 16 + c;
            if (col < N) {
                float bv = BIAS ? bias[col] : 0.f;
                #pragma unroll
                for (int i = 0; i < 4; ++i) {
                    int row = m0 + wm * 64 + mi * 16 + g * 4 + i;
                    size_t off = (size_t)row * N + col;
                    float v = acc[mi][ni][i] + bv;
                    if (RES) v += res[off];
                    if (OUTBF16) ((short*)outp)[off] = f2b(v);
                    else         ((float*)outp)[off] = v;
                }
            }
        }
    }
    #undef STA3
    #undef STB3
    #undef LDA3
    #undef LDB3
    #undef MFMA8
}

// ---------------- gemm4: 256x256 tile, BK=64, 8 waves, 128KB LDS (logits) ----------------
// f32 output uses nontemporal stores (write-only stream; avoid L2/L3 pollution).
template <bool BIAS, bool RES, bool OUTBF16>
__global__ __launch_bounds__(512, 2) void gemm4(
    const short* __restrict__ A, const short* __restrict__ Bt,
    const float* __restrict__ bias, const float* __restrict__ res,
    void* __restrict__ outp, int N, int lda, int ldb, int nrowsB, int KT) {
    __shared__ __align__(16) short L[65536];
    const int t = threadIdx.x;
    const int lane = t & 63;
    const int w = t >> 6;
    const int wm = w >> 2, wn = w & 3;
    const int c = lane & 15, g = lane >> 4;

    const int nwg = (int)gridDim.x, cpx = nwg >> 3;
    const int wg = ((int)blockIdx.x & 7) * cpx + ((int)blockIdx.x >> 3);
    const int m0 = (wg & 15) << 8;
    const int n0 = (wg >> 4) << 8;

    const int sub0 = t & 63;
    const int seg0 = sub0 >> 4, r0 = sub0 & 15;
    const int slab0 = t >> 6, slab1 = slab0 + 8;
    const size_t aoff0 = (size_t)(m0 + slab0 * 16 + r0) * lda + seg0 * 8;
    const size_t aoff1 = (size_t)(m0 + slab1 * 16 + r0) * lda + seg0 * 8;
    int br0 = n0 + slab0 * 16 + r0; if (br0 > nrowsB - 1) br0 = nrowsB - 1;
    int br1 = n0 + slab1 * 16 + r0; if (br1 > nrowsB - 1) br1 = nrowsB - 1;
    const size_t boff0 = (size_t)br0 * ldb + seg0 * 8;
    const size_t boff1 = (size_t)br1 * ldb + seg0 * 8;

    char* Lb = (char*)L;
    const int rb = g * 256 + c * 16;

    #define STA4(p, kh, kt) do { \
        gload16(A + aoff0 + (kt) * 64 + (kh) * 32, Lb + ((p)*2+(kh))*16384 + w*1024); \
        gload16(A + aoff1 + (kt) * 64 + (kh) * 32, Lb + ((p)*2+(kh))*16384 + 8192 + w*1024); } while (0)
    #define STB4(p, kh, kt) do { \
        gload16(Bt + boff0 + (kt) * 64 + (kh) * 32, Lb + 65536 + ((p)*2+(kh))*16384 + w*1024); \
        gload16(Bt + boff1 + (kt) * 64 + (kh) * 32, Lb + 65536 + ((p)*2+(kh))*16384 + 8192 + w*1024); } while (0)
    #define LDA4(p, ks, mi) (*(const short8v*)(Lb + ((p)*2+(ks))*16384 + (wm*8+(mi))*1024 + rb))
    #define LDB4(p, ks, ni) (*(const short8v*)(Lb + 65536 + ((p)*2+(ks))*16384 + (wn*4+(ni))*1024 + rb))
    #define MFMAQ(MB) do { \
        _Pragma("unroll") for (int mi_ = 0; mi_ < 4; ++mi_) \
        _Pragma("unroll") for (int ni_ = 0; ni_ < 4; ++ni_) \
            mfma_n(acc[(MB) + mi_][ni_], av[mi_], bv[ni_]); } while (0)

    f32x4 acc[8][4] = {};
    short8v av[4], bv[4];

    STA4(0, 0, 0); STB4(0, 0, 0); STA4(0, 1, 0); STB4(0, 1, 0);
    VMN(4);
    BARX();
    asm volatile("s_nop 7\n\ts_nop 7");

    #define TILE4(p, pn, tc, stg2) do { \
        _Pragma("unroll") for (int mi = 0; mi < 4; ++mi) av[mi] = LDA4(p, 0, mi); \
        _Pragma("unroll") for (int ni = 0; ni < 4; ++ni) bv[ni] = LDB4(p, 0, ni); \
        if (stg2) STA4(pn, 0, (tc) + 1); \
        BARX(); \
        __builtin_amdgcn_s_setprio(1); MFMAQ(0); __builtin_amdgcn_s_setprio(0); \
        BARX(); \
        _Pragma("unroll") for (int mi = 0; mi < 4; ++mi) av[mi] = LDA4(p, 0, mi + 4); \
        if (stg2) { STB4(pn, 0, (tc) + 1); VMN(4); } else { VMN(0); } \
        BARX(); \
        __builtin_amdgcn_s_setprio(1); MFMAQ(4); __builtin_amdgcn_s_setprio(0); \
        BARX(); \
        _Pragma("unroll") for (int mi = 0; mi < 4; ++mi) av[mi] = LDA4(p, 1, mi); \
        _Pragma("unroll") for (int ni = 0; ni < 4; ++ni) bv[ni] = LDB4(p, 1, ni); \
        if (stg2) STA4(pn, 1, (tc) + 1); \
        BARX(); \
        __builtin_amdgcn_s_setprio(1); MFMAQ(0); __builtin_amdgcn_s_setprio(0); \
        BARX(); \
        _Pragma("unroll") for (int mi = 0; mi < 4; ++mi) av[mi] = LDA4(p, 1, mi + 4); \
        if (stg2) { STB4(pn, 1, (tc) + 1); VMN(4); } \
        BARX(); \
        __builtin_amdgcn_s_setprio(1); MFMAQ(4); __builtin_amdgcn_s_setprio(0); \
        BARX(); \
    } while (0)

    for (int kt = 0; kt < KT; kt += 2) {
        TILE4(0, 1, kt, true);
        TILE4(1, 0, kt + 1, (kt + 2 < KT));
    }
    #undef TILE4

    MFMA_FENCE();
    #pragma unroll
    for (int mi = 0; mi < 8; ++mi) {
        #pragma unroll
        for (int ni = 0; ni < 4; ++ni) {
            int col = n0 + wn * 64 + ni * 16 + c;
            if (col < N) {
                float bvv = BIAS ? bias[col] : 0.f;
                #pragma unroll
                for (int i = 0; i < 4; ++i) {
                    int row = m0 + wm * 128 + mi * 16 + g * 4 + i;
                    size_t off = (size_t)row * N + col;
                    float v = acc[mi][ni][i] + bvv;
                    if (RES) v += res[off];
                    if (OUTBF16) ((short*)outp)[off] = f2b(v);
                    else __builtin_nontemporal_store(v, &((float*)outp)[off]);
                }
            }
        }
    }
    #undef STA4
    #undef STB4
    #undef LDA4
    #undef LDB4
    #undef MFMAQ
}

// ---------------- flash attention (balanced qt; exp2 via amdgcn builtin) ----------------
__global__ __launch_bounds__(256, 2) void attn_fwd(
    const short* __restrict__ qkv, const short* __restrict__ vt,
    short* __restrict__ o) {
    const int id = blockIdx.x;
    const int bh = id & 31;
    const int qs = id >> 5;
    const int qt = (qs < 8) ? qs : 23 - qs;
    const int b = bh >> 4, h = bh & 15;
    const int t = threadIdx.x, lane = t & 63, w = t >> 6;
    const int c = lane & 15, g = lane >> 4;
    __shared__ __align__(16) short Ks[128 * 72];
    __shared__ __align__(16) short Vs[64 * 136];
    __shared__ __align__(16) short Ps[128 * 136];

    #pragma unroll
    for (int i = 0; i < 4; ++i) {
        int idx = t + i * 256, r = idx >> 3, seg = idx & 7;
        *(int4*)&Ps[r * 136 + seg * 8] =
            *(const int4*)(qkv + (size_t)(b * 2048 + qt * 128 + r) * 3072 + h * 64 + seg * 8);
    }
    __syncthreads();
    short8v qf[2][2];
    #pragma unroll
    for (int mi = 0; mi < 2; ++mi)
        #pragma unroll
        for (int kk = 0; kk < 2; ++kk)
            qf[mi][kk] = *(const short8v*)&Ps[(w * 32 + mi * 16 + c) * 136 + kk * 32 + g * 8];

    f32x4 oacc[2][4] = {};
    float mrow[2][4], lrow[2][4];
    #pragma unroll
    for (int mi = 0; mi < 2; ++mi)
        #pragma unroll
        for (int i = 0; i < 4; ++i) { mrow[mi][i] = -3.0e38f; lrow[mi][i] = 0.f; }

    for (int jt = 0; jt <= qt; ++jt) {
        __syncthreads();
        #pragma unroll
        for (int i = 0; i < 4; ++i) {
            int idx = t + i * 256, r = idx >> 3, seg = idx & 7;
            *(int4*)&Ks[r * 72 + seg * 8] =
                *(const int4*)(qkv + (size_t)(b * 2048 + jt * 128 + r) * 3072
                               + 1024 + h * 64 + seg * 8);
        }
        #pragma unroll
        for (int i = 0; i < 4; ++i) {
            int idx = t + i * 256, d = idx >> 4, seg = idx & 15;
            *(int4*)&Vs[d * 136 + seg * 8] =
                *(const int4*)(vt + (size_t)(bh * 64 + d) * 2048 + jt * 128 + seg * 8);
        }
        __syncthreads();
        f32x4 sacc[2][8] = {};
        #pragma unroll
        for (int kk = 0; kk < 2; ++kk) {
            short8v kf[8];
            #pragma unroll
            for (int ni = 0; ni < 8; ++ni)
                kf[ni] = *(const short8v*)&Ks[(ni * 16 + c) * 72 + kk * 32 + g * 8];
            #pragma unroll
            for (int mi = 0; mi < 2; ++mi)
                #pragma unroll
                for (int ni = 0; ni < 8; ++ni) {
                    if (kk == 0) mfma_f(sacc[mi][ni], qf[mi][kk], kf[ni]);
                    else         mfma_n(sacc[mi][ni], qf[mi][kk], kf[ni]);
                }
        }
        MFMA_FENCE();
        if (jt == qt) {
            #pragma unroll
            for (int mi = 0; mi < 2; ++mi)
                #pragma unroll
                for (int ni = 0; ni < 8; ++ni)
                    #pragma unroll
                    for (int i = 0; i < 4; ++i) {
                        int qrow = w * 32 + mi * 16 + g * 4 + i;
                        int kcol = ni * 16 + c;
                        if (kcol > qrow) sacc[mi][ni][i] = -3.0e38f;
                    }
        }
        #pragma unroll
        for (int mi = 0; mi < 2; ++mi) {
            #pragma unroll
            for (int i = 0; i < 4; ++i) {
                float mx = sacc[mi][0][i];
                #pragma unroll
                for (int ni = 1; ni < 8; ++ni) mx = fmaxf(mx, sacc[mi][ni][i]);
                #pragma unroll
                for (int off = 1; off < 16; off <<= 1) mx = fmaxf(mx, __shfl_xor(mx, off, 64));
                float mnew = fmaxf(mrow[mi][i], mx);
                float alpha = __builtin_amdgcn_exp2f(mrow[mi][i] - mnew);
                mrow[mi][i] = mnew;
                float ls = 0.f;
                #pragma unroll
                for (int ni = 0; ni < 8; ++ni) {
                    float p = __builtin_amdgcn_exp2f(sacc[mi][ni][i] - mnew);
                    sacc[mi][ni][i] = p;
                    ls += p;
                }
                #pragma unroll
                for (int off = 1; off < 16; off <<= 1) ls += __shfl_xor(ls, off, 64);
                lrow[mi][i] = lrow[mi][i] * alpha + ls;
                #pragma unroll
                for (int df = 0; df < 4; ++df) oacc[mi][df][i] *= alpha;
            }
        }
        #pragma unroll
        for (int mi = 0; mi < 2; ++mi)
            #pragma unroll
            for (int ni = 0; ni < 8; ++ni)
                #pragma unroll
                for (int i = 0; i < 4; ++i)
                    Ps[(w * 32 + mi * 16 + g * 4 + i) * 136 + ni * 16 + c] =
                        f2b(sacc[mi][ni][i]);
        #pragma unroll
        for (int kk = 0; kk < 4; ++kk) {
            short8v pf[2], vf[4];
            #pragma unroll
            for (int mi = 0; mi < 2; ++mi)
                pf[mi] = *(const short8v*)&Ps[(w * 32 + mi * 16 + c) * 136 + kk * 32 + g * 8];
            #pragma unroll
            for (int df = 0; df < 4; ++df)
                vf[df] = *(const short8v*)&Vs[(df * 16 + c) * 136 + kk * 32 + g * 8];
            #pragma unroll
            for (int mi = 0; mi < 2; ++mi)
                #pragma unroll
                for (int df = 0; df < 4; ++df) {
                    if (kk == 0) mfma_f(oacc[mi][df], pf[mi], vf[df]);
                    else         mfma_n(oacc[mi][df], pf[mi], vf[df]);
                }
        }
    }
    MFMA_FENCE();
    #pragma unroll
    for (int mi = 0; mi < 2; ++mi)
        #pragma unroll
        for (int df = 0; df < 4; ++df)
            #pragma unroll
            for (int i = 0; i < 4; ++i) {
                int qrow = qt * 128 + w * 32 + mi * 16 + g * 4 + i;
                float v = oacc[mi][df][i] / lrow[mi][i];
                o[(size_t)(b * 2048 + qrow) * 1024 + h * 64 + df * 16 + c] = f2b(v);
            }
}

extern "C" void kernel_launch(void* const* d_in, const int* in_sizes, int n_in,
                              void* d_out, int out_size, void* d_ws, size_t ws_size,
                              hipStream_t stream) {
    (void)in_sizes; (void)n_in; (void)out_size; (void)ws_size;
    const int*   tokens = (const int*)d_in[0];
    const float* temb   = (const float*)d_in[1];
    const float* anw    = (const float*)d_in[2];
    const float* wqkv   = (const float*)d_in[3];
    const float* wo     = (const float*)d_in[4];
    const float* fnw    = (const float*)d_in[5];
    const float* fw1    = (const float*)d_in[6];
    const float* fb1    = (const float*)d_in[7];
    const float* fw2    = (const float*)d_in[8];
    const float* fb2    = (const float*)d_in[9];
    const float* finw   = (const float*)d_in[10];
    const float* lw     = (const float*)d_in[11];
    const float* lb     = (const float*)d_in[12];

    char* ws = (char*)d_ws;
    float* x    = (float*)(ws + 0);            // 4096x1024 f32
    short* hb   = (short*)(ws + 16777216);     // 4096x1024 bf16
    short* qkv  = (short*)(ws + 25165824);     // 4096x3072 bf16
    short* ao   = (short*)(ws + 50331648);     // 4096x1024 bf16
    short* gb   = (short*)(ws + 103448576);    // 4096x2752 bf16 (K-padded)
    short* vtb  = (short*)(ws + 125992960);    // 32x64x2048 bf16
    float* ct   = (float*)(ws + 134381568);    // 2048x32 f32
    float* st   = (float*)(ws + 134643712);    // 2048x32 f32
    short* qkvT = (short*)(ws + 134905856);    // 4 x [3072][1024] bf16
    short* woT  = (short*)(ws + 160071680);    // 4 x [1024][1024]
    short* fw1T = (short*)(ws + 168460288);    // 4 x [5632][1024] (interleaved u1/gate)
    short* fw2T = (short*)(ws + 214597632);    // 4 x [1024][2752]
    short* logT = (short*)(ws + 237142016);    // [32000][1024]

    rope_table_k<<<256, 256, 0, stream>>>(ct, st);
    embed_k<<<4096, 256, 0, stream>>>(tokens, temb, x);

    wconv_k<<<dim3(96, 32, 4), 256, 0, stream>>>(
        wqkv, qkvT, 1024, 3072, 1024, (size_t)1024 * 3072, (size_t)3072 * 1024, 0);
    wconv_k<<<dim3(32, 32, 4), 256, 0, stream>>>(
        wo, woT, 1024, 1024, 1024, (size_t)1024 * 1024, (size_t)1024 * 1024, 0);
    wconv_k<<<dim3(171, 32, 4), 256, 0, stream>>>(
        fw1, fw1T, 1024, 5460, 1024, (size_t)1024 * 5460, (size_t)5632 * 1024, 1);
    wconv_k<<<dim3(32, 86, 4), 256, 0, stream>>>(
        fw2, fw2T, 2730, 1024, 2752, (size_t)2730 * 1024, (size_t)1024 * 2752, 0);
    wconv_k<<<dim3(1000, 32, 1), 256, 0, stream>>>(
        lw, logT, 1024, 32000, 1024, 0, 0, 0);

    for (int l = 0; l < 4; ++l) {
        rmsnorm_k<<<4096, 256, 0, stream>>>(x, anw + l * 1024, hb);
        gemm3<false, false, true, 1><<<32 * 12, 512, 0, stream>>>(
            hb, qkvT + (size_t)l * 3072 * 1024, nullptr, nullptr, qkv,
            3072, 1024, 1024, 3072, 16, ct, st, vtb);
        attn_fwd<<<512, 256, 0, stream>>>(qkv, vtb, ao);
        gemm2h<false, true, false><<<512, 256, 0, stream>>>(
            ao, woT + (size_t)l * 1024 * 1024, nullptr, x, x, 1024, 1024, 1024, 32);
        rmsnorm_k<<<4096, 256, 0, stream>>>(x, fnw + l * 1024, hb);
        gemm3<false, false, true, 2><<<32 * 22, 512, 0, stream>>>(
            hb, fw1T + (size_t)l * 5632 * 1024, fb1 + l * 5460, nullptr, gb,
            2752, 1024, 1024, 5632, 16, nullptr, nullptr, nullptr);
        gemm2h<true, true, false><<<512, 256, 0, stream>>>(
            gb, fw2T + (size_t)l * 1024 * 2752, fb2 + l * 1024, x, x, 1024, 2752, 2752, 86);
    }
    rmsnorm_k<<<4096, 256, 0, stream>>>(x, finw, hb);
    gemm4<true, false, false><<<2000, 512, 0, stream>>>(
        hb, logT, lb, nullptr, d_out, 32000, 1024, 1024, 32000, 16);
}

// Round 17
// 1739.347 us; speedup vs baseline: 1.0056x; 1.0056x over previous
//
#include <hip/hip_runtime.h>
#include <math.h>
#include <stdint.h>

// Llama forward on MI355X. Round 17: revert round-16's nontemporal-store regression
// (it inflated WRITE_SIZE 512->697MB via broken write-combining on scattered dword
// stores). Exact round-15 configuration = measured best (1740us).

using short8v = __attribute__((ext_vector_type(8))) short;
using f32x4   = __attribute__((ext_vector_type(4))) float;

__device__ __forceinline__ float b2f(short s) {
    union { unsigned u; float f; } v; v.u = ((unsigned)(unsigned short)s) << 16; return v.f;
}
__device__ __forceinline__ short f2b(float f) {
    union { float f; unsigned u; } v; v.f = f;
    unsigned r = v.u + 0x7FFFu + ((v.u >> 16) & 1u);
    return (short)(r >> 16);
}

__device__ __forceinline__ void mfma_n(f32x4& d, short8v a, short8v b) {
    asm("v_mfma_f32_16x16x32_bf16 %0, %1, %2, %0" : "+v"(d) : "v"(a), "v"(b));
}
__device__ __forceinline__ void mfma_f(f32x4& d, short8v a, short8v b) {
    asm("s_nop 1\n\tv_mfma_f32_16x16x32_bf16 %0, %1, %2, %0" : "+v"(d) : "v"(a), "v"(b));
}
#define MFMA_FENCE() do { __builtin_amdgcn_sched_barrier(0); \
    asm volatile("s_nop 7\n\ts_nop 7"); \
    __builtin_amdgcn_sched_barrier(0); } while (0)

__device__ __forceinline__ void gload16(const void* g, void* l) {
    __builtin_amdgcn_global_load_lds(
        (const __attribute__((address_space(1))) unsigned int*)(uintptr_t)g,
        (__attribute__((address_space(3))) unsigned int*)(uintptr_t)l,
        16, 0, 0);
}

#define BARX() do { asm volatile("" ::: "memory"); \
    __builtin_amdgcn_s_barrier(); asm volatile("" ::: "memory"); } while (0)
#define VMN(n) asm volatile("s_waitcnt vmcnt(" #n ")" ::: "memory")
#define LGKM0() do { asm volatile("s_waitcnt lgkmcnt(0)" ::: "memory"); \
    __builtin_amdgcn_sched_barrier(0); } while (0)

// ---------------- rope tables ----------------
__global__ void rope_table_k(float* __restrict__ ct, float* __restrict__ st) {
    int i = blockIdx.x * 256 + threadIdx.x;
    int n = i >> 5, j = i & 31;
    float freq = expf(-(float)j * (9.210340371976184f / 32.f));
    float a = (float)n * freq;
    ct[i] = cosf(a);
    st[i] = sinf(a);
}

// ---------------- embedding gather ----------------
__global__ void embed_k(const int* __restrict__ tok, const float* __restrict__ emb,
                        float* __restrict__ x) {
    int row = blockIdx.x;
    int tk = tok[row];
    const float4* src = (const float4*)(emb + (size_t)tk * 1024);
    float4* dst = (float4*)(x + (size_t)row * 1024);
    dst[threadIdx.x] = src[threadIdx.x];
}

// ---------------- weight convert+transpose: f32 [K][N] -> bf16 [rows][Kpad] ----------------
__global__ void wconv_k(const float* __restrict__ W, short* __restrict__ T,
                        int K, int N, int Kpad,
                        size_t w_lstride, size_t t_lstride, int ilv) {
    W += blockIdx.z * w_lstride;
    T += blockIdx.z * t_lstride;
    int n0 = blockIdx.x * 32, k0 = blockIdx.y * 32;
    __shared__ float tile[32][33];
    int t = threadIdx.x;
    int kk = t >> 3, ns = (t & 7) * 4;
    float4 v = make_float4(0.f, 0.f, 0.f, 0.f);
    int gk = k0 + kk;
    if (gk < K) {
        if (n0 + ns + 3 < N) {
            v = *(const float4*)(W + (size_t)gk * N + n0 + ns);
        } else {
            float tmp[4] = {0.f, 0.f, 0.f, 0.f};
            #pragma unroll
            for (int j = 0; j < 4; ++j)
                if (n0 + ns + j < N) tmp[j] = W[(size_t)gk * N + n0 + ns + j];
            v = make_float4(tmp[0], tmp[1], tmp[2], tmp[3]);
        }
    }
    tile[kk][ns + 0] = v.x; tile[kk][ns + 1] = v.y;
    tile[kk][ns + 2] = v.z; tile[kk][ns + 3] = v.w;
    __syncthreads();
    int nn = t >> 3, ks = (t & 7) * 4;
    short o[4];
    #pragma unroll
    for (int j = 0; j < 4; ++j) o[j] = f2b(tile[ks + j][nn]);
    int oc = n0 + nn;
    int dr = oc;
    if (ilv) {
        if (oc < 2730) dr = ((oc >> 4) << 5) + (oc & 15);
        else { int jj = oc - 2730; dr = ((jj >> 4) << 5) + 16 + (jj & 15); }
    }
    *(int2*)(T + (size_t)dr * Kpad + k0 + ks) = *(int2*)o;
}

// ---------------- rmsnorm: f32 in -> bf16 out ----------------
__global__ void rmsnorm_k(const float* __restrict__ x, const float* __restrict__ wt,
                          short* __restrict__ out) {
    int row = blockIdx.x;
    int t = threadIdx.x;
    const float* xr = x + (size_t)row * 1024;
    float4 v = ((const float4*)xr)[t];
    float ss = v.x * v.x + v.y * v.y + v.z * v.z + v.w * v.w;
    #pragma unroll
    for (int off = 32; off > 0; off >>= 1) ss += __shfl_down(ss, off, 64);
    __shared__ float red[4];
    if ((t & 63) == 0) red[t >> 6] = ss;
    __syncthreads();
    float tot = red[0] + red[1] + red[2] + red[3];
    float inv = rsqrtf(tot * (1.f / 1024.f) + 1.1920929e-7f);
    float4 wv = ((const float4*)wt)[t];
    int2 pk;
    pk.x = (int)(unsigned short)f2b(v.x * inv * wv.x) |
           ((int)(unsigned short)f2b(v.y * inv * wv.y) << 16);
    pk.y = (int)(unsigned short)f2b(v.z * inv * wv.z) |
           ((int)(unsigned short)f2b(v.w * inv * wv.w) << 16);
    *(int2*)(out + (size_t)row * 1024 + t * 4) = pk;
}

// ---------------- gemm2h: 64x128 drain-style, 4 blocks/CU (wo, ff2) ----------------
template <bool BIAS, bool RES, bool OUTBF16>
__global__ __launch_bounds__(256, 4) void gemm2h(
    const short* __restrict__ A, const short* __restrict__ Bt,
    const float* __restrict__ bias, const float* __restrict__ res,
    void* __restrict__ outp, int N, int lda, int ldb, int ksteps) {
    __shared__ __align__(16) short As[64 * 32];
    __shared__ __align__(16) short Bs[128 * 32];
    const int t = threadIdx.x;
    const int lane = t & 63;
    const int w = t >> 6, wm = w >> 1, wn = w & 1;
    const int c = lane & 15, g = lane >> 4;

    const int nwg = (int)gridDim.x;
    const int cpx = nwg >> 3;
    const int wg = ((int)blockIdx.x & 7) * cpx + ((int)blockIdx.x >> 3);
    const int m0 = (wg & 63) << 6;
    const int n0 = (wg >> 6) << 7;

    const int srow = w * 16 + (lane >> 2);
    const int sseg = (lane & 3) * 8;
    const short* ga0 = A  + (size_t)(m0 + srow) * lda + sseg;
    const short* gb0 = Bt + (size_t)(n0 + w * 32 + (lane >> 2)) * ldb + sseg;
    const short* gb1 = Bt + (size_t)(n0 + w * 32 + 16 + (lane >> 2)) * ldb + sseg;
    short* la0 = &As[w * 512];
    short* lb0 = &Bs[(w * 2 + 0) * 512];
    short* lb1 = &Bs[(w * 2 + 1) * 512];

    f32x4 acc[2][4] = {};

    for (int kt = 0; kt < ksteps; ++kt) {
        const int k0 = kt << 5;
        __syncthreads();
        gload16(ga0 + k0, la0);
        gload16(gb0 + k0, lb0);
        gload16(gb1 + k0, lb1);
        __syncthreads();
        short8v af[2], bf[4];
        #pragma unroll
        for (int mi = 0; mi < 2; ++mi)
            af[mi] = *(const short8v*)&As[(wm * 32 + mi * 16 + c) * 32 + g * 8];
        #pragma unroll
        for (int ni = 0; ni < 4; ++ni)
            bf[ni] = *(const short8v*)&Bs[(wn * 64 + ni * 16 + c) * 32 + g * 8];
        #pragma unroll
        for (int mi = 0; mi < 2; ++mi)
            #pragma unroll
            for (int ni = 0; ni < 4; ++ni)
                mfma_n(acc[mi][ni], af[mi], bf[ni]);
    }
    MFMA_FENCE();
    #pragma unroll
    for (int mi = 0; mi < 2; ++mi) {
        #pragma unroll
        for (int ni = 0; ni < 4; ++ni) {
            int col = n0 + wn * 64 + ni * 16 + c;
            if (col < N) {
                float bv = BIAS ? bias[col] : 0.f;
                #pragma unroll
                for (int i = 0; i < 4; ++i) {
                    int row = m0 + wm * 32 + mi * 16 + g * 4 + i;
                    size_t off = (size_t)row * N + col;
                    float v = acc[mi][ni][i] + bv;
                    if (RES) v += res[off];
                    if (OUTBF16) ((short*)outp)[off] = f2b(v);
                    else         ((float*)outp)[off] = v;
                }
            }
        }
    }
}

// ---------------- gemm3: 8-phase counted-vmcnt 128x256, BK=64, 8 waves ----------------
// EPI: 0 = plain epilogue, 1 = rope (qkv), 2 = geglu (ff1, interleaved layout).
template <bool BIAS, bool RES, bool OUTBF16, int EPI>
__global__ __launch_bounds__(512, 1) void gemm3(
    const short* __restrict__ A, const short* __restrict__ Bt,
    const float* __restrict__ bias, const float* __restrict__ res,
    void* __restrict__ outp, int N, int lda, int ldb, int nrowsB, int KT,
    const float* __restrict__ ct, const float* __restrict__ st,
    short* __restrict__ vtb) {
    __shared__ __align__(16) short L[49152];
    const int t = threadIdx.x;
    const int lane = t & 63;
    const int w = t >> 6;
    const int wm = w >> 2, wn = w & 3;
    const int c = lane & 15, g = lane >> 4;

    const int nwg = (int)gridDim.x, cpx = nwg >> 3;
    const int wg = ((int)blockIdx.x & 7) * cpx + ((int)blockIdx.x >> 3);
    const int m0 = (wg & 31) << 7;
    const int n0 = (wg >> 5) << 8;

    const int rS = t >> 3, sS = t & 7;
    const int sSw = (sS ^ (rS & 7)) << 3;
    size_t aoffh[2], broff[2][2];
    #pragma unroll
    for (int h = 0; h < 2; ++h)
        aoffh[h] = (size_t)(m0 + h * 64 + rS) * lda + sSw;
    #pragma unroll
    for (int h = 0; h < 2; ++h)
        #pragma unroll
        for (int i = 0; i < 2; ++i) {
            int brow = n0 + h * 128 + rS + i * 64;
            if (brow > nrowsB - 1) brow = nrowsB - 1;
            broff[h][i] = (size_t)brow * ldb + sSw;
        }
    short* ldsA[2][2];
    short* ldsB[2][2];
    #pragma unroll
    for (int p = 0; p < 2; ++p)
        #pragma unroll
        for (int h = 0; h < 2; ++h) {
            ldsA[p][h] = &L[(p * 2 + h) * 4096 + w * 512];
            ldsB[p][h] = &L[16384 + (p * 2 + h) * 8192 + w * 512];
        }

    const int cb0 = ((g * 8) ^ ((c & 7) * 8));
    const int vbA0 = wm * 4096 + c * 64 + cb0;
    const int vbA1 = vbA0 ^ 32;
    const int vbB0 = 16384 + (wn >> 1) * 8192 + (wn & 1) * 4096 + c * 64 + cb0;
    const int vbB1 = vbB0 ^ 32;

    #define STA3(p, h, kt) gload16(A + aoffh[h] + (kt) * 64, ldsA[p][h])
    #define STB3(p, h, kt) do { \
        gload16(Bt + broff[h][0] + (kt) * 64, ldsB[p][h]); \
        gload16(Bt + broff[h][1] + (kt) * 64, ldsB[p][h] + 4096); } while (0)
    #define LDA3(p, mi, ks) (*(const short8v*)&L[(p) * 8192 + (mi) * 1024 + ((ks) ? vbA1 : vbA0)])
    #define LDB3(p, ni, ks) (*(const short8v*)&L[(p) * 16384 + (ni) * 1024 + ((ks) ? vbB1 : vbB0)])
    #define MFMA8(MLO, NLO, BV) do { \
        _Pragma("unroll") for (int ks_ = 0; ks_ < 2; ++ks_) \
        _Pragma("unroll") for (int mi_ = 0; mi_ < 2; ++mi_) \
        _Pragma("unroll") for (int ni_ = 0; ni_ < 2; ++ni_) \
            mfma_n(acc[(MLO) + mi_][(NLO) + ni_], av[(MLO) + mi_][ks_], BV[(NLO) + ni_][ks_]); \
        } while (0)

    f32x4 acc[4][4] = {};
    short8v av[4][2], bc[4][2], bn[4][2];

    STB3(0, 1, 0); STB3(0, 0, 0); STA3(0, 0, 0); STA3(0, 1, 0);
    STB3(1, 1, 1); STB3(1, 0, 1); STA3(1, 0, 1); STA3(1, 1, 1);
    VMN(6);
    BARX();
    #pragma unroll
    for (int ni = 0; ni < 4; ++ni)
        #pragma unroll
        for (int ks = 0; ks < 2; ++ks)
            bc[ni][ks] = LDB3(0, ni, ks);
    LGKM0();
    BARX();
    asm volatile("s_nop 7\n\ts_nop 7");

    for (int KB = 0; KB < KT; KB += 2) {
        const bool st1 = (KB + 2 < KT);
        const bool st2 = (KB + 3 < KT);
        // ph1
        #pragma unroll
        for (int mi = 0; mi < 2; ++mi)
            #pragma unroll
            for (int ks = 0; ks < 2; ++ks) av[mi][ks] = LDA3(0, mi, ks);
        if (st1) STB3(0, 1, KB + 2);
        BARX();
        __builtin_amdgcn_s_setprio(1); MFMA8(0, 0, bc); __builtin_amdgcn_s_setprio(0);
        BARX();
        // ph2
        #pragma unroll
        for (int mi = 2; mi < 4; ++mi)
            #pragma unroll
            for (int ks = 0; ks < 2; ++ks) av[mi][ks] = LDA3(0, mi, ks);
        if (st1) { STB3(0, 0, KB + 2); VMN(6); } else { VMN(2); }
        BARX();
        __builtin_amdgcn_s_setprio(1); MFMA8(2, 0, bc); __builtin_amdgcn_s_setprio(0);
        BARX();
        // ph3
        #pragma unroll
        for (int ni = 0; ni < 2; ++ni)
            #pragma unroll
            for (int ks = 0; ks < 2; ++ks) bn[ni][ks] = LDB3(1, ni, ks);
        if (st1) STA3(0, 0, KB + 2);
        BARX();
        __builtin_amdgcn_s_setprio(1); MFMA8(0, 2, bc); __builtin_amdgcn_s_setprio(0);
        BARX();
        // ph4
        #pragma unroll
        for (int ni = 2; ni < 4; ++ni)
            #pragma unroll
            for (int ks = 0; ks < 2; ++ks) bn[ni][ks] = LDB3(1, ni, ks);
        if (st1) { STA3(0, 1, KB + 2); VMN(6); } else { VMN(0); }
        BARX();
        __builtin_amdgcn_s_setprio(1); MFMA8(2, 2, bc); __builtin_amdgcn_s_setprio(0);
        BARX();
        // ph5
        #pragma unroll
        for (int mi = 0; mi < 2; ++mi)
            #pragma unroll
            for (int ks = 0; ks < 2; ++ks) av[mi][ks] = LDA3(1, mi, ks);
        if (st2) STB3(1, 1, KB + 3);
        BARX();
        __builtin_amdgcn_s_setprio(1); MFMA8(0, 0, bn); __builtin_amdgcn_s_setprio(0);
        BARX();
        // ph6
        #pragma unroll
        for (int mi = 2; mi < 4; ++mi)
            #pragma unroll
            for (int ks = 0; ks < 2; ++ks) av[mi][ks] = LDA3(1, mi, ks);
        if (st2) STB3(1, 0, KB + 3);
        if (st1) VMN(6);
        BARX();
        __builtin_amdgcn_s_setprio(1); MFMA8(2, 0, bn); __builtin_amdgcn_s_setprio(0);
        BARX();
        // ph7
        if (st1) {
            #pragma unroll
            for (int ni = 0; ni < 2; ++ni)
                #pragma unroll
                for (int ks = 0; ks < 2; ++ks) bc[ni][ks] = LDB3(0, ni, ks);
        }
        if (st2) STA3(1, 0, KB + 3);
        BARX();
        __builtin_amdgcn_s_setprio(1); MFMA8(0, 2, bn); __builtin_amdgcn_s_setprio(0);
        BARX();
        // ph8
        if (st1) {
            #pragma unroll
            for (int ni = 2; ni < 4; ++ni)
                #pragma unroll
                for (int ks = 0; ks < 2; ++ks) bc[ni][ks] = LDB3(0, ni, ks);
        }
        if (st2) STA3(1, 1, KB + 3);
        if (st1) VMN(6);
        BARX();
        __builtin_amdgcn_s_setprio(1); MFMA8(2, 2, bn); __builtin_amdgcn_s_setprio(0);
        BARX();
    }

    MFMA_FENCE();

    if (EPI == 1) {
        const int colbase = n0 + wn * 64;
        const int sec = colbase >> 10;
        if (sec < 2) {
            const float sc = (sec == 0) ? 0.18033688011112042f : 1.0f;
            #pragma unroll
            for (int mi = 0; mi < 4; ++mi)
                #pragma unroll
                for (int ni = 0; ni < 2; ++ni) {
                    const int col = colbase + ni * 16 + c;
                    const int jj = ni * 16 + c;
                    #pragma unroll
                    for (int i = 0; i < 4; ++i) {
                        int row = m0 + wm * 64 + mi * 16 + g * 4 + i;
                        int n = row & 2047;
                        float cv = ct[n * 32 + jj], sv = st[n * 32 + jj];
                        float a = acc[mi][ni][i], b = acc[mi][ni + 2][i];
                        ((short*)outp)[(size_t)row * N + col]      = f2b((a * cv - b * sv) * sc);
                        ((short*)outp)[(size_t)row * N + col + 32] = f2b((b * cv + a * sv) * sc);
                    }
                }
        } else {
            const int h64 = (colbase - 2048) >> 6;
            #pragma unroll
            for (int mi = 0; mi < 4; ++mi) {
                const int r0 = m0 + wm * 64 + mi * 16 + g * 4;
                const int bb = r0 >> 11, nn = r0 & 2047;
                #pragma unroll
                for (int ni = 0; ni < 4; ++ni) {
                    const int d = ni * 16 + c;
                    short s4[4];
                    #pragma unroll
                    for (int i = 0; i < 4; ++i) s4[i] = f2b(acc[mi][ni][i]);
                    *(int2*)(vtb + (size_t)((bb * 16 + h64) * 64 + d) * 2048 + nn) =
                        *(int2*)s4;
                }
            }
        }
        return;
    }

    if (EPI == 2) {
        const int colbase = n0 + wn * 64;
        #pragma unroll
        for (int np = 0; np < 2; ++np) {
            const int j = ((colbase >> 5) + np) * 16 + c;
            if (j < 2730) {
                const float bu = bias[j], bg = bias[2730 + j];
                #pragma unroll
                for (int mi = 0; mi < 4; ++mi)
                    #pragma unroll
                    for (int i = 0; i < 4; ++i) {
                        int row = m0 + wm * 64 + mi * 16 + g * 4 + i;
                        float u1v = acc[mi][2 * np][i] + bu;
                        float gv  = acc[mi][2 * np + 1][i] + bg;
                        float val = 0.5f * gv * (1.f + erff(gv * 0.7071067811865475f)) * u1v;
                        ((short*)outp)[(size_t)row * 2752 + j] = f2b(val);
                    }
            } else if (j < 2752) {
                #pragma unroll
                for (int mi = 0; mi < 4; ++mi)
                    #pragma unroll
                    for (int i = 0; i < 4; ++i) {
                        int row = m0 + wm * 64 + mi * 16 + g * 4 + i;
                        ((short*)outp)[(size_t)row * 2752 + j] = 0;
                    }
            }
        }
        return;
    }

    #pragma unroll
    for (int mi = 0; mi < 4; ++mi) {
        #pragma unroll
        for (int ni = 0; ni < 4; ++ni) {
            int col = n0 + wn * 64 + ni * 16 + c;
            if (col < N) {
                float bv = BIAS ? bias[col] : 0.f;
                #pragma unroll
                for (int i = 0; i < 4; ++i) {
                    int row = m0 + wm * 64 + mi * 16 + g * 4 + i;
                    size_t off = (size_t)row * N + col;
                    float v = acc[mi][ni][i] + bv;
                    if (RES) v += res[off];
                    if (OUTBF16) ((short*)outp)[off] = f2b(v);
                    else         ((float*)outp)[off] = v;
                }
            }
        }
    }
    #undef STA3
    #undef STB3
    #undef LDA3
    #undef LDB3
    #undef MFMA8
}

// ---------------- gemm4: 256x256 tile, BK=64, 8 waves, 128KB LDS (logits) ----------------
template <bool BIAS, bool RES, bool OUTBF16>
__global__ __launch_bounds__(512, 2) void gemm4(
    const short* __restrict__ A, const short* __restrict__ Bt,
    const float* __restrict__ bias, const float* __restrict__ res,
    void* __restrict__ outp, int N, int lda, int ldb, int nrowsB, int KT) {
    __shared__ __align__(16) short L[65536];
    const int t = threadIdx.x;
    const int lane = t & 63;
    const int w = t >> 6;
    const int wm = w >> 2, wn = w & 3;
    const int c = lane & 15, g = lane >> 4;

    const int nwg = (int)gridDim.x, cpx = nwg >> 3;
    const int wg = ((int)blockIdx.x & 7) * cpx + ((int)blockIdx.x >> 3);
    const int m0 = (wg & 15) << 8;
    const int n0 = (wg >> 4) << 8;

    const int sub0 = t & 63;
    const int seg0 = sub0 >> 4, r0 = sub0 & 15;
    const int slab0 = t >> 6, slab1 = slab0 + 8;
    const size_t aoff0 = (size_t)(m0 + slab0 * 16 + r0) * lda + seg0 * 8;
    const size_t aoff1 = (size_t)(m0 + slab1 * 16 + r0) * lda + seg0 * 8;
    int br0 = n0 + slab0 * 16 + r0; if (br0 > nrowsB - 1) br0 = nrowsB - 1;
    int br1 = n0 + slab1 * 16 + r0; if (br1 > nrowsB - 1) br1 = nrowsB - 1;
    const size_t boff0 = (size_t)br0 * ldb + seg0 * 8;
    const size_t boff1 = (size_t)br1 * ldb + seg0 * 8;

    char* Lb = (char*)L;
    const int rb = g * 256 + c * 16;

    #define STA4(p, kh, kt) do { \
        gload16(A + aoff0 + (kt) * 64 + (kh) * 32, Lb + ((p)*2+(kh))*16384 + w*1024); \
        gload16(A + aoff1 + (kt) * 64 + (kh) * 32, Lb + ((p)*2+(kh))*16384 + 8192 + w*1024); } while (0)
    #define STB4(p, kh, kt) do { \
        gload16(Bt + boff0 + (kt) * 64 + (kh) * 32, Lb + 65536 + ((p)*2+(kh))*16384 + w*1024); \
        gload16(Bt + boff1 + (kt) * 64 + (kh) * 32, Lb + 65536 + ((p)*2+(kh))*16384 + 8192 + w*1024); } while (0)
    #define LDA4(p, ks, mi) (*(const short8v*)(Lb + ((p)*2+(ks))*16384 + (wm*8+(mi))*1024 + rb))
    #define LDB4(p, ks, ni) (*(const short8v*)(Lb + 65536 + ((p)*2+(ks))*16384 + (wn*4+(ni))*1024 + rb))
    #define MFMAQ(MB) do { \
        _Pragma("unroll") for (int mi_ = 0; mi_ < 4; ++mi_) \
        _Pragma("unroll") for (int ni_ = 0; ni_ < 4; ++ni_) \
            mfma_n(acc[(MB) + mi_][ni_], av[mi_], bv[ni_]); } while (0)

    f32x4 acc[8][4] = {};
    short8v av[4], bv[4];

    STA4(0, 0, 0); STB4(0, 0, 0); STA4(0, 1, 0); STB4(0, 1, 0);
    VMN(4);
    BARX();
    asm volatile("s_nop 7\n\ts_nop 7");

    #define TILE4(p, pn, tc, stg2) do { \
        _Pragma("unroll") for (int mi = 0; mi < 4; ++mi) av[mi] = LDA4(p, 0, mi); \
        _Pragma("unroll") for (int ni = 0; ni < 4; ++ni) bv[ni] = LDB4(p, 0, ni); \
        if (stg2) STA4(pn, 0, (tc) + 1); \
        BARX(); \
        __builtin_amdgcn_s_setprio(1); MFMAQ(0); __builtin_amdgcn_s_setprio(0); \
        BARX(); \
        _Pragma("unroll") for (int mi = 0; mi < 4; ++mi) av[mi] = LDA4(p, 0, mi + 4); \
        if (stg2) { STB4(pn, 0, (tc) + 1); VMN(4); } else { VMN(0); } \
        BARX(); \
        __builtin_amdgcn_s_setprio(1); MFMAQ(4); __builtin_amdgcn_s_setprio(0); \
        BARX(); \
        _Pragma("unroll") for (int mi = 0; mi < 4; ++mi) av[mi] = LDA4(p, 1, mi); \
        _Pragma("unroll") for (int ni = 0; ni < 4; ++ni) bv[ni] = LDB4(p, 1, ni); \
        if (stg2) STA4(pn, 1, (tc) + 1); \
        BARX(); \
        __builtin_amdgcn_s_setprio(1); MFMAQ(0); __builtin_amdgcn_s_setprio(0); \
        BARX(); \
        _Pragma("unroll") for (int mi = 0; mi < 4; ++mi) av[mi] = LDA4(p, 1, mi + 4); \
        if (stg2) { STB4(pn, 1, (tc) + 1); VMN(4); } \
        BARX(); \
        __builtin_amdgcn_s_setprio(1); MFMAQ(4); __builtin_amdgcn_s_setprio(0); \
        BARX(); \
    } while (0)

    for (int kt = 0; kt < KT; kt += 2) {
        TILE4(0, 1, kt, true);
        TILE4(1, 0, kt + 1, (kt + 2 < KT));
    }
    #undef TILE4

    MFMA_FENCE();
    #pragma unroll
    for (int mi = 0; mi < 8; ++mi) {
        #pragma unroll
        for (int ni = 0; ni < 4; ++ni) {
            int col = n0 + wn * 64 + ni * 16 + c;
            if (col < N) {
                float bvv = BIAS ? bias[col] : 0.f;
                #pragma unroll
                for (int i = 0; i < 4; ++i) {
                    int row = m0 + wm * 128 + mi * 16 + g * 4 + i;
                    size_t off = (size_t)row * N + col;
                    float v = acc[mi][ni][i] + bvv;
                    if (RES) v += res[off];
                    if (OUTBF16) ((short*)outp)[off] = f2b(v);
                    else         ((float*)outp)[off] = v;
                }
            }
        }
    }
    #undef STA4
    #undef STB4
    #undef LDA4
    #undef LDB4
    #undef MFMAQ
}

// ---------------- flash attention (balanced qt; exp2 via amdgcn builtin) ----------------
__global__ __launch_bounds__(256, 2) void attn_fwd(
    const short* __restrict__ qkv, const short* __restrict__ vt,
    short* __restrict__ o) {
    const int id = blockIdx.x;
    const int bh = id & 31;
    const int qs = id >> 5;
    const int qt = (qs < 8) ? qs : 23 - qs;
    const int b = bh >> 4, h = bh & 15;
    const int t = threadIdx.x, lane = t & 63, w = t >> 6;
    const int c = lane & 15, g = lane >> 4;
    __shared__ __align__(16) short Ks[128 * 72];
    __shared__ __align__(16) short Vs[64 * 136];
    __shared__ __align__(16) short Ps[128 * 136];

    #pragma unroll
    for (int i = 0; i < 4; ++i) {
        int idx = t + i * 256, r = idx >> 3, seg = idx & 7;
        *(int4*)&Ps[r * 136 + seg * 8] =
            *(const int4*)(qkv + (size_t)(b * 2048 + qt * 128 + r) * 3072 + h * 64 + seg * 8);
    }
    __syncthreads();
    short8v qf[2][2];
    #pragma unroll
    for (int mi = 0; mi < 2; ++mi)
        #pragma unroll
        for (int kk = 0; kk < 2; ++kk)
            qf[mi][kk] = *(const short8v*)&Ps[(w * 32 + mi * 16 + c) * 136 + kk * 32 + g * 8];

    f32x4 oacc[2][4] = {};
    float mrow[2][4], lrow[2][4];
    #pragma unroll
    for (int mi = 0; mi < 2; ++mi)
        #pragma unroll
        for (int i = 0; i < 4; ++i) { mrow[mi][i] = -3.0e38f; lrow[mi][i] = 0.f; }

    for (int jt = 0; jt <= qt; ++jt) {
        __syncthreads();
        #pragma unroll
        for (int i = 0; i < 4; ++i) {
            int idx = t + i * 256, r = idx >> 3, seg = idx & 7;
            *(int4*)&Ks[r * 72 + seg * 8] =
                *(const int4*)(qkv + (size_t)(b * 2048 + jt * 128 + r) * 3072
                               + 1024 + h * 64 + seg * 8);
        }
        #pragma unroll
        for (int i = 0; i < 4; ++i) {
            int idx = t + i * 256, d = idx >> 4, seg = idx & 15;
            *(int4*)&Vs[d * 136 + seg * 8] =
                *(const int4*)(vt + (size_t)(bh * 64 + d) * 2048 + jt * 128 + seg * 8);
        }
        __syncthreads();
        f32x4 sacc[2][8] = {};
        #pragma unroll
        for (int kk = 0; kk < 2; ++kk) {
            short8v kf[8];
            #pragma unroll
            for (int ni = 0; ni < 8; ++ni)
                kf[ni] = *(const short8v*)&Ks[(ni * 16 + c) * 72 + kk * 32 + g * 8];
            #pragma unroll
            for (int mi = 0; mi < 2; ++mi)
                #pragma unroll
                for (int ni = 0; ni < 8; ++ni) {
                    if (kk == 0) mfma_f(sacc[mi][ni], qf[mi][kk], kf[ni]);
                    else         mfma_n(sacc[mi][ni], qf[mi][kk], kf[ni]);
                }
        }
        MFMA_FENCE();
        if (jt == qt) {
            #pragma unroll
            for (int mi = 0; mi < 2; ++mi)
                #pragma unroll
                for (int ni = 0; ni < 8; ++ni)
                    #pragma unroll
                    for (int i = 0; i < 4; ++i) {
                        int qrow = w * 32 + mi * 16 + g * 4 + i;
                        int kcol = ni * 16 + c;
                        if (kcol > qrow) sacc[mi][ni][i] = -3.0e38f;
                    }
        }
        #pragma unroll
        for (int mi = 0; mi < 2; ++mi) {
            #pragma unroll
            for (int i = 0; i < 4; ++i) {
                float mx = sacc[mi][0][i];
                #pragma unroll
                for (int ni = 1; ni < 8; ++ni) mx = fmaxf(mx, sacc[mi][ni][i]);
                #pragma unroll
                for (int off = 1; off < 16; off <<= 1) mx = fmaxf(mx, __shfl_xor(mx, off, 64));
                float mnew = fmaxf(mrow[mi][i], mx);
                float alpha = __builtin_amdgcn_exp2f(mrow[mi][i] - mnew);
                mrow[mi][i] = mnew;
                float ls = 0.f;
                #pragma unroll
                for (int ni = 0; ni < 8; ++ni) {
                    float p = __builtin_amdgcn_exp2f(sacc[mi][ni][i] - mnew);
                    sacc[mi][ni][i] = p;
                    ls += p;
                }
                #pragma unroll
                for (int off = 1; off < 16; off <<= 1) ls += __shfl_xor(ls, off, 64);
                lrow[mi][i] = lrow[mi][i] * alpha + ls;
                #pragma unroll
                for (int df = 0; df < 4; ++df) oacc[mi][df][i] *= alpha;
            }
        }
        #pragma unroll
        for (int mi = 0; mi < 2; ++mi)
            #pragma unroll
            for (int ni = 0; ni < 8; ++ni)
                #pragma unroll
                for (int i = 0; i < 4; ++i)
                    Ps[(w * 32 + mi * 16 + g * 4 + i) * 136 + ni * 16 + c] =
                        f2b(sacc[mi][ni][i]);
        #pragma unroll
        for (int kk = 0; kk < 4; ++kk) {
            short8v pf[2], vf[4];
            #pragma unroll
            for (int mi = 0; mi < 2; ++mi)
                pf[mi] = *(const short8v*)&Ps[(w * 32 + mi * 16 + c) * 136 + kk * 32 + g * 8];
            #pragma unroll
            for (int df = 0; df < 4; ++df)
                vf[df] = *(const short8v*)&Vs[(df * 16 + c) * 136 + kk * 32 + g * 8];
            #pragma unroll
            for (int mi = 0; mi < 2; ++mi)
                #pragma unroll
                for (int df = 0; df < 4; ++df) {
                    if (kk == 0) mfma_f(oacc[mi][df], pf[mi], vf[df]);
                    else         mfma_n(oacc[mi][df], pf[mi], vf[df]);
                }
        }
    }
    MFMA_FENCE();
    #pragma unroll
    for (int mi = 0; mi < 2; ++mi)
        #pragma unroll
        for (int df = 0; df < 4; ++df)
            #pragma unroll
            for (int i = 0; i < 4; ++i) {
                int qrow = qt * 128 + w * 32 + mi * 16 + g * 4 + i;
                float v = oacc[mi][df][i] / lrow[mi][i];
                o[(size_t)(b * 2048 + qrow) * 1024 + h * 64 + df * 16 + c] = f2b(v);
            }
}

extern "C" void kernel_launch(void* const* d_in, const int* in_sizes, int n_in,
                              void* d_out, int out_size, void* d_ws, size_t ws_size,
                              hipStream_t stream) {
    (void)in_sizes; (void)n_in; (void)out_size; (void)ws_size;
    const int*   tokens = (const int*)d_in[0];
    const float* temb   = (const float*)d_in[1];
    const float* anw    = (const float*)d_in[2];
    const float* wqkv   = (const float*)d_in[3];
    const float* wo     = (const float*)d_in[4];
    const float* fnw    = (const float*)d_in[5];
    const float* fw1    = (const float*)d_in[6];
    const float* fb1    = (const float*)d_in[7];
    const float* fw2    = (const float*)d_in[8];
    const float* fb2    = (const float*)d_in[9];
    const float* finw   = (const float*)d_in[10];
    const float* lw     = (const float*)d_in[11];
    const float* lb     = (const float*)d_in[12];

    char* ws = (char*)d_ws;
    float* x    = (float*)(ws + 0);            // 4096x1024 f32
    short* hb   = (short*)(ws + 16777216);     // 4096x1024 bf16
    short* qkv  = (short*)(ws + 25165824);     // 4096x3072 bf16
    short* ao   = (short*)(ws + 50331648);     // 4096x1024 bf16
    short* gb   = (short*)(ws + 103448576);    // 4096x2752 bf16 (K-padded)
    short* vtb  = (short*)(ws + 125992960);    // 32x64x2048 bf16
    float* ct   = (float*)(ws + 134381568);    // 2048x32 f32
    float* st   = (float*)(ws + 134643712);    // 2048x32 f32
    short* qkvT = (short*)(ws + 134905856);    // 4 x [3072][1024] bf16
    short* woT  = (short*)(ws + 160071680);    // 4 x [1024][1024]
    short* fw1T = (short*)(ws + 168460288);    // 4 x [5632][1024] (interleaved u1/gate)
    short* fw2T = (short*)(ws + 214597632);    // 4 x [1024][2752]
    short* logT = (short*)(ws + 237142016);    // [32000][1024]

    rope_table_k<<<256, 256, 0, stream>>>(ct, st);
    embed_k<<<4096, 256, 0, stream>>>(tokens, temb, x);

    wconv_k<<<dim3(96, 32, 4), 256, 0, stream>>>(
        wqkv, qkvT, 1024, 3072, 1024, (size_t)1024 * 3072, (size_t)3072 * 1024, 0);
    wconv_k<<<dim3(32, 32, 4), 256, 0, stream>>>(
        wo, woT, 1024, 1024, 1024, (size_t)1024 * 1024, (size_t)1024 * 1024, 0);
    wconv_k<<<dim3(171, 32, 4), 256, 0, stream>>>(
        fw1, fw1T, 1024, 5460, 1024, (size_t)1024 * 5460, (size_t)5632 * 1024, 1);
    wconv_k<<<dim3(32, 86, 4), 256, 0, stream>>>(
        fw2, fw2T, 2730, 1024, 2752, (size_t)2730 * 1024, (size_t)1024 * 2752, 0);
    wconv_k<<<dim3(1000, 32, 1), 256, 0, stream>>>(
        lw, logT, 1024, 32000, 1024, 0, 0, 0);

    for (int l = 0; l < 4; ++l) {
        rmsnorm_k<<<4096, 256, 0, stream>>>(x, anw + l * 1024, hb);
        gemm3<false, false, true, 1><<<32 * 12, 512, 0, stream>>>(
            hb, qkvT + (size_t)l * 3072 * 1024, nullptr, nullptr, qkv,
            3072, 1024, 1024, 3072, 16, ct, st, vtb);
        attn_fwd<<<512, 256, 0, stream>>>(qkv, vtb, ao);
        gemm2h<false, true, false><<<512, 256, 0, stream>>>(
            ao, woT + (size_t)l * 1024 * 1024, nullptr, x, x, 1024, 1024, 1024, 32);
        rmsnorm_k<<<4096, 256, 0, stream>>>(x, fnw + l * 1024, hb);
        gemm3<false, false, true, 2><<<32 * 22, 512, 0, stream>>>(
            hb, fw1T + (size_t)l * 5632 * 1024, fb1 + l * 5460, nullptr, gb,
            2752, 1024, 1024, 5632, 16, nullptr, nullptr, nullptr);
        gemm2h<true, true, false><<<512, 256, 0, stream>>>(
            gb, fw2T + (size_t)l * 1024 * 2752, fb2 + l * 1024, x, x, 1024, 2752, 2752, 86);
    }
    rmsnorm_k<<<4096, 256, 0, stream>>>(x, finw, hb);
    gemm4<true, false, false><<<2000, 512, 0, stream>>>(
        hb, logT, lb, nullptr, d_out, 32000, 1024, 1024, 32000, 16);
}